// Round 14
// baseline (490.199 us; speedup 1.0000x reference)
//
#include <hip/hip_runtime.h>
#include <math.h>

#define NB 4096
#define NR 49
#define NS 50
#define ND 512
#define NK 100
#define NT 7            // n-tiles of 16 cols (112 >= 100)
#define KSTEPS 16       // 512 / 32
#define FRAGS (NT * KSTEPS * 64 * 8)   // 57344 ushorts (114688 B) per weight matrix

typedef __attribute__((ext_vector_type(8))) short short8;
typedef __attribute__((ext_vector_type(4))) float f32x4;

__device__ __forceinline__ unsigned short f32_bf16(float f) {
    union { float f; unsigned u; } x; x.f = f;
    return (unsigned short)((x.u + 0x7fffu + ((x.u >> 16) & 1u)) >> 16);  // RNE
}
__device__ __forceinline__ unsigned cvt_pk_bf16(float lo, float hi) {
    unsigned r;
    asm("v_cvt_pk_bf16_f32 %0, %1, %2" : "=v"(r) : "v"(lo), "v"(hi));
    return r;
}
__device__ __forceinline__ float fast_tanh(float x) {
    const float ax = fabsf(x);
    const float e = __expf(2.f * ax);            // inf for large ax -> r = 1
    const float r = 1.f - 2.f / (e + 1.f);
    return copysignf(r, x);
}

// ---------------------------------------------------------------------------
// Pre-pass: 2 weight matrices [512][100] f32 -> bf16 MFMA B-fragments.
// (Only w_Vi_0 / w_Vt_1 needed: broadcast conditioning branches cancel in
//  softmax; the two attention passes are fully independent.)
// frag(t, gk): lane l holds W[k = gk*32 + (l>>4)*8 + j][col = t*16 + (l&15)].
// ---------------------------------------------------------------------------
__global__ void preswz_kernel(const float* __restrict__ w0, const float* __restrict__ w1,
                              unsigned short* __restrict__ ws)
{
    const int l  = threadIdx.x;          // 64
    const int gk = blockIdx.x & 15;
    const int t  = blockIdx.x >> 4;      // 0..6
    const int m  = blockIdx.y;           // 0..1
    const float* W = m ? w1 : w0;
    const int col = t * 16 + (l & 15);
    const int k0  = gk * 32 + (l >> 4) * 8;
    unsigned short* o = ws + (size_t)m * FRAGS + ((size_t)(t * 16 + gk) * 64 + l) * 8;
#pragma unroll
    for (int j = 0; j < 8; ++j) {
        float v = (col < NK) ? W[(size_t)(k0 + j) * NK + col] : 0.f;
        o[j] = f32_bf16(v);
    }
}

// ---------------------------------------------------------------------------
// Main kernel: one block per (batch, pass), 512 threads (8 waves).
// NO LDS feature tile: the MFMA A-fragment is a per-lane CONTIGUOUS 32-B
// global read (feat[arow*512 + ks*32 + g*8]), so fragments stream directly
// from L1/L2/L3 — the LDS pipe (measured ~80% busy incl. 7.5e7 conflict
// cycles in R9-R13, the cross-round invariant ceiling) is bypassed entirely.
// Wave w = (pair q = w>>1, row-half mh = w&1): n-tiles {2q,2q+1} (q=3: one)
// x row-tiles {2mh,2mh+1}. f32->bf16 at fragment build (cvt_pk x4).
// Epilogue -> softmax -> unrolled global wsum -> atomicAdd (out pre-zeroed;
// 2 commutative f32 adds = deterministic).
// ---------------------------------------------------------------------------
struct SM {
    float part[8][64];       // per-wave row partials (rows mh*32..+32 valid)
    float P[64];
};

__global__ __launch_bounds__(512, 4) void coattn_main(
    const float* __restrict__ ifeat, const float* __restrict__ tfeat,
    const float* __restrict__ wPi0, const float* __restrict__ bPi0,
    const float* __restrict__ wPi1, const float* __restrict__ bPi1,
    const unsigned short* __restrict__ wsW, float* __restrict__ out)
{
    __shared__ SM sm;
    const int pass = blockIdx.x & 1;
    const int b    = blockIdx.x >> 1;
    const int tid  = threadIdx.x;

    const float* feat = pass ? (tfeat + (size_t)b * NS * ND) : (ifeat + (size_t)b * NR * ND);
    const int nrows  = pass ? NS : NR;
    const int nclamp = nrows - 1;
    const unsigned short* wsR = wsW + (size_t)pass * FRAGS;
    const float* wPiRow = pass ? (wPi1 + NK) : wPi0;
    const float* bvec   = pass ? bPi1 : bPi0;

    const int lane = tid & 63, wid = tid >> 6;
    const int colg = lane & 15, g = lane >> 4;
    const int q  = wid >> 1;          // tile-pair 0..3
    const int mh = wid & 1;           // row-half
    const int t0 = q * 2;
    const int two = (q < 3);          // q==3 owns only tile 6

    // per-lane A-fragment row bases (clamped; padded rows masked at softmax)
    const float* fA[2];
#pragma unroll
    for (int rl = 0; rl < 2; ++rl) {
        const int r0 = (mh * 2 + rl) * 16 + colg;
        const int arow = (r0 < nclamp) ? r0 : nclamp;
        fA[rl] = feat + ((size_t)arow << 9) + (g << 3);
    }
    const unsigned short* wl0 = wsR + ((size_t)t0 * 16 * 64 + lane) * 8;
    const unsigned short* wl1 = wl0 + (size_t)16 * 64 * 8;

    f32x4 acc[2][2];
#pragma unroll
    for (int rl = 0; rl < 2; ++rl)
#pragma unroll
        for (int tl = 0; tl < 2; ++tl) acc[rl][tl] = f32x4{0.f, 0.f, 0.f, 0.f};

    // ---- GEMM: 16 k-steps, fragments straight from global (L1/L2-hot)
#pragma unroll
    for (int ks = 0; ks < KSTEPS; ++ks) {
        const short8 wf0 = *reinterpret_cast<const short8*>(wl0 + ks * 512);
        short8 wf1 = {};
        if (two) wf1 = *reinterpret_cast<const short8*>(wl1 + ks * 512);
#pragma unroll
        for (int rl = 0; rl < 2; ++rl) {
            const float4 fa = *reinterpret_cast<const float4*>(fA[rl] + ks * 32);
            const float4 fb = *reinterpret_cast<const float4*>(fA[rl] + ks * 32 + 4);
            uint4 ap;
            ap.x = cvt_pk_bf16(fa.x, fa.y); ap.y = cvt_pk_bf16(fa.z, fa.w);
            ap.z = cvt_pk_bf16(fb.x, fb.y); ap.w = cvt_pk_bf16(fb.z, fb.w);
            const short8 a = *reinterpret_cast<const short8*>(&ap);
            acc[rl][0] = __builtin_amdgcn_mfma_f32_16x16x32_bf16(a, wf0, acc[rl][0], 0, 0, 0);
            if (two)
                acc[rl][1] = __builtin_amdgcn_mfma_f32_16x16x32_bf16(a, wf1, acc[rl][1], 0, 0, 0);
        }
    }

    // ---- epilogue: per-wave row partials (sum over this wave's 1-2 tiles)
    {
        const int c0 = (t0 + 0) * 16 + colg;
        const int c1 = (t0 + 1) * 16 + colg;
        const float w0 = (c0 < NK) ? wPiRow[c0] : 0.f;
        const float w1 = (two && c1 < NK) ? wPiRow[c1] : 0.f;
        float sp[2][4];
#pragma unroll
        for (int rl = 0; rl < 2; ++rl)
#pragma unroll
            for (int i = 0; i < 4; ++i) {
                float v = fast_tanh(acc[rl][0][i]) * w0;
                if (two) v += fast_tanh(acc[rl][1][i]) * w1;
                sp[rl][i] = v;
            }
#pragma unroll
        for (int off = 1; off < 16; off <<= 1)
#pragma unroll
            for (int rl = 0; rl < 2; ++rl)
#pragma unroll
                for (int i = 0; i < 4; ++i)
                    sp[rl][i] += __shfl_xor(sp[rl][i], off);
        if (colg == 0) {
#pragma unroll
            for (int rl = 0; rl < 2; ++rl)
#pragma unroll
                for (int i = 0; i < 4; ++i)
                    sm.part[wid][(mh * 2 + rl) * 16 + g * 4 + i] = sp[rl][i];
        }
    }
    __syncthreads();

    if (tid < 64) {   // softmax over rows; row r lives in waves {2q + (r>=32)}
        const int hb = (tid >= 32) ? 1 : 0;
        float v = (tid < nrows) ? bvec[tid] : 0.f;
#pragma unroll
        for (int qq = 0; qq < 4; ++qq) v += sm.part[2 * qq + hb][tid];
        v = (tid < nrows) ? v : -3.0e38f;
        float mx = v;
#pragma unroll
        for (int off = 32; off; off >>= 1) mx = fmaxf(mx, __shfl_xor(mx, off));
        const float e = (tid < nrows) ? __expf(v - mx) : 0.f;
        float su = e;
#pragma unroll
        for (int off = 32; off; off >>= 1) su += __shfl_xor(su, off);
        sm.P[tid] = e / su;
    }
    __syncthreads();

    // ---- weighted sum (unrolled; loads pipeline ahead of the fadd chain)
    {
        float v = 0.f;
        const float* fp = feat + tid;
        if (pass == 0) {
#pragma unroll
            for (int r = 0; r < NR; ++r) v += sm.P[r] * fp[(size_t)r << 9];
        } else {
#pragma unroll
            for (int r = 0; r < NS; ++r) v += sm.P[r] * fp[(size_t)r << 9];
        }
        atomicAdd(&out[(size_t)b * ND + tid], v);
    }
}

extern "C" void kernel_launch(void* const* d_in, const int* in_sizes, int n_in,
                              void* d_out, int out_size, void* d_ws, size_t ws_size,
                              hipStream_t stream) {
    const float* ifeat = (const float*)d_in[0];
    const float* tfeat = (const float*)d_in[1];
    const float* wVi0  = (const float*)d_in[2];
    const float* wPi0  = (const float*)d_in[4];
    const float* bPi0  = (const float*)d_in[5];
    const float* wVt1  = (const float*)d_in[7];
    const float* wPi1  = (const float*)d_in[8];
    const float* bPi1  = (const float*)d_in[9];
    float* outp = (float*)d_out;
    unsigned short* wsW = (unsigned short*)d_ws;   // 2*114688 = 229376 B

    hipMemsetAsync(outp, 0, (size_t)NB * ND * sizeof(float), stream);
    hipLaunchKernelGGL(preswz_kernel, dim3(NT * KSTEPS, 2), dim3(64), 0, stream,
                       wVi0, wVt1, wsW);
    hipLaunchKernelGGL(coattn_main, dim3(2 * NB), dim3(512), 0, stream,
                       ifeat, tfeat, wPi0, bPi0, wPi1, bPi1, wsW, outp);
}

// Round 15
// 380.334 us; speedup vs baseline: 1.2889x; 1.2889x over previous
//
#include <hip/hip_runtime.h>
#include <math.h>

#define NB 4096
#define NR 49
#define NS 50
#define ND 512
#define NK 100
#define NT 7            // n-tiles of 16 cols (112 >= 100)
#define KSTEPS 16       // 512 / 32
#define NBATCH 8        // batches per block
#define NGRP (NB / NBATCH)             // 512 groups; grid = 2*NGRP
#define FRAGS (NT * KSTEPS * 64 * 8)   // 57344 ushorts (114688 B) per weight matrix

typedef __attribute__((ext_vector_type(8))) short short8;
typedef __attribute__((ext_vector_type(4))) float f32x4;

__device__ __forceinline__ unsigned short f32_bf16(float f) {
    union { float f; unsigned u; } x; x.f = f;
    return (unsigned short)((x.u + 0x7fffu + ((x.u >> 16) & 1u)) >> 16);  // RNE
}
__device__ __forceinline__ float bf16_f32(unsigned short h) {
    union { unsigned u; float f; } x; x.u = ((unsigned)h) << 16;
    return x.f;
}
__device__ __forceinline__ unsigned cvt_pk_bf16(float lo, float hi) {
    unsigned r;
    asm("v_cvt_pk_bf16_f32 %0, %1, %2" : "=v"(r) : "v"(lo), "v"(hi));
    return r;
}
__device__ __forceinline__ float fast_tanh(float x) {
    const float ax = fabsf(x);
    const float e = __expf(2.f * ax);            // inf for large ax -> r = 1
    const float r = 1.f - 2.f / (e + 1.f);
    return copysignf(r, x);
}

// ---------------------------------------------------------------------------
// Pre-pass: 2 weight matrices [512][100] f32 -> bf16 MFMA B-fragments.
// (Only w_Vi_0 / w_Vt_1 needed: broadcast conditioning branches cancel in
//  softmax; the two attention passes are fully independent.)
// frag(t, gk): lane l holds W[k = gk*32 + (l>>4)*8 + j][col = t*16 + (l&15)].
// ---------------------------------------------------------------------------
__global__ void preswz_kernel(const float* __restrict__ w0, const float* __restrict__ w1,
                              unsigned short* __restrict__ ws)
{
    const int l  = threadIdx.x;          // 64
    const int gk = blockIdx.x & 15;
    const int t  = blockIdx.x >> 4;      // 0..6
    const int m  = blockIdx.y;           // 0..1
    const float* W = m ? w1 : w0;
    const int col = t * 16 + (l & 15);
    const int k0  = gk * 32 + (l >> 4) * 8;
    unsigned short* o = ws + (size_t)m * FRAGS + ((size_t)(t * 16 + gk) * 64 + l) * 8;
#pragma unroll
    for (int j = 0; j < 8; ++j) {
        float v = (col < NK) ? W[(size_t)(k0 + j) * NK + col] : 0.f;
        o[j] = f32_bf16(v);
    }
}

// ---------------------------------------------------------------------------
// Main kernel: one block per (8-batch group, pass), 512 threads, 1 block/CU.
// IN-BLOCK SOFTWARE PIPELINE across batches: batch i+1's global loads are
// issued before batch i's GEMM and land during it (T14); the cvt+LDS-write
// happens after the GEMM. So the HBM stream (the largest pipe-term) overlaps
// the LDS/MFMA/VALU phases inside the same waves — no reliance on cross-block
// overlap (which R6-R14 showed is defeated by lockstep convoys).
// Per batch: GEMM (R12 wave map: q=wid>>1 owns n-tiles {2q,2q+1}, mh=wid&1
// owns row-half) -> epilogue -> softmax -> wsum from LDS bf16 -> atomicAdd
// (out pre-zeroed; 2 commutative f32 adds = deterministic).
// ---------------------------------------------------------------------------
struct SM {
    short bufA[NS * ND];     // 51200 B bf16 tile, 16B-chunk XOR swizzle
    short bufB[NS * ND];
    float part[8][64];
    float P[64];
};

__global__ __launch_bounds__(512, 2) void coattn_main(
    const float* __restrict__ ifeat, const float* __restrict__ tfeat,
    const float* __restrict__ wPi0, const float* __restrict__ bPi0,
    const float* __restrict__ wPi1, const float* __restrict__ bPi1,
    const unsigned short* __restrict__ wsW, float* __restrict__ out)
{
    __shared__ SM sm;
    const int pass = blockIdx.x & 1;
    const int grp  = blockIdx.x >> 1;
    const int tid  = threadIdx.x;

    const int nrows  = pass ? NS : NR;
    const int nclamp = nrows - 1;
    const int tail   = pass ? 128 : 64;          // items = nrows*64 = 6*512 + tail
    const float* featB = (pass ? tfeat : ifeat) + (size_t)grp * NBATCH * nrows * ND;
    const unsigned short* wsR = wsW + (size_t)pass * FRAGS;
    const float* wPiRow = pass ? (wPi1 + NK) : wPi0;
    const float* bvec   = pass ? bPi1 : bPi0;

    const int lane = tid & 63, wid = tid >> 6;
    const int colg = lane & 15, g = lane >> 4;
    const int q  = wid >> 1;          // tile-pair 0..3
    const int mh = wid & 1;           // row-half
    const int t0 = q * 2;
    const int two = (q < 3);          // q==3 owns only tile 6
    const int wch = tid >> 3, wlo = tid & 7;     // wsum column addressing

    int arow_[2], aswz_[2];
#pragma unroll
    for (int rl = 0; rl < 2; ++rl) {
        const int r0 = (mh * 2 + rl) * 16 + colg;
        arow_[rl] = (r0 < nclamp) ? r0 : nclamp;
        aswz_[rl] = arow_[rl] & 7;
    }
    const unsigned short* wl0 = wsR + ((size_t)t0 * 16 * 64 + lane) * 8;
    const unsigned short* wl1 = wl0 + (size_t)16 * 64 * 8;

    // stage-load: 7 items/thread (item u: it = tid + u*512 -> row it>>6, c it&63)
#define LOADF(SRC, LA, LB)                                                      \
    _Pragma("unroll") for (int u = 0; u < 7; ++u) {                             \
        const int it = tid + (u << 9);                                          \
        const bool on = (u < 6) || (tid < tail);                                \
        const int r = it >> 6, c = it & 63;                                     \
        const float* p = (SRC) + (r << 9) + (c << 3);                           \
        LA[u] = on ? *reinterpret_cast<const float4*>(p) : float4{0.f,0.f,0.f,0.f}; \
        LB[u] = on ? *reinterpret_cast<const float4*>(p + 4) : float4{0.f,0.f,0.f,0.f}; \
    }
#define WRITEF(DST, LA, LB)                                                     \
    _Pragma("unroll") for (int u = 0; u < 7; ++u) {                             \
        const int it = tid + (u << 9);                                          \
        if ((u < 6) || (tid < tail)) {                                          \
            const int r = it >> 6, c = it & 63;                                 \
            uint4 v;                                                            \
            v.x = cvt_pk_bf16(LA[u].x, LA[u].y); v.y = cvt_pk_bf16(LA[u].z, LA[u].w); \
            v.z = cvt_pk_bf16(LB[u].x, LB[u].y); v.w = cvt_pk_bf16(LB[u].z, LB[u].w); \
            *reinterpret_cast<uint4*>(&(DST)[(r << 9) + ((c ^ (r & 7)) << 3)]) = v; \
        }                                                                       \
    }

    // ---- prologue: stage batch 0 into bufA
    {
        float4 La[7], Lb[7];
        LOADF(featB, La, Lb)
        WRITEF(sm.bufA, La, Lb)
    }
    __syncthreads();

#pragma unroll 1
    for (int i = 0; i < NBATCH; ++i) {
        short* curb = (i & 1) ? sm.bufB : sm.bufA;
        short* nxtb = (i & 1) ? sm.bufA : sm.bufB;
        const float* fnext = featB + (size_t)(i + 1) * nrows * ND;

        // ---- issue next batch's loads (land during GEMM below)
        float4 La[7], Lb[7];
        if (i + 1 < NBATCH) { LOADF(fnext, La, Lb) }

        // ---- GEMM batch i from curb (bf16 LDS, R10-proven addressing)
        f32x4 acc[2][2];
#pragma unroll
        for (int rl = 0; rl < 2; ++rl)
#pragma unroll
            for (int tl = 0; tl < 2; ++tl) acc[rl][tl] = f32x4{0.f, 0.f, 0.f, 0.f};
#pragma unroll
        for (int ks = 0; ks < KSTEPS; ++ks) {
            const short8 wf0 = *reinterpret_cast<const short8*>(wl0 + ks * 512);
            short8 wf1 = {};
            if (two) wf1 = *reinterpret_cast<const short8*>(wl1 + ks * 512);
            const int q0 = (ks << 2) + g;
#pragma unroll
            for (int rl = 0; rl < 2; ++rl) {
                const short8 a = *reinterpret_cast<const short8*>(
                    &curb[(arow_[rl] << 9) + ((q0 ^ aswz_[rl]) << 3)]);
                acc[rl][0] = __builtin_amdgcn_mfma_f32_16x16x32_bf16(a, wf0, acc[rl][0], 0, 0, 0);
                if (two)
                    acc[rl][1] = __builtin_amdgcn_mfma_f32_16x16x32_bf16(a, wf1, acc[rl][1], 0, 0, 0);
            }
        }

        // ---- write next batch's tile (loads have had the whole GEMM to land)
        if (i + 1 < NBATCH) { WRITEF(nxtb, La, Lb) }

        // ---- epilogue: per-wave row partials
        {
            const int c0 = (t0 + 0) * 16 + colg;
            const int c1 = (t0 + 1) * 16 + colg;
            const float w0 = (c0 < NK) ? wPiRow[c0] : 0.f;
            const float w1 = (two && c1 < NK) ? wPiRow[c1] : 0.f;
            float sp[2][4];
#pragma unroll
            for (int rl = 0; rl < 2; ++rl)
#pragma unroll
                for (int ii = 0; ii < 4; ++ii) {
                    float v = fast_tanh(acc[rl][0][ii]) * w0;
                    if (two) v += fast_tanh(acc[rl][1][ii]) * w1;
                    sp[rl][ii] = v;
                }
#pragma unroll
            for (int off = 1; off < 16; off <<= 1)
#pragma unroll
                for (int rl = 0; rl < 2; ++rl)
#pragma unroll
                    for (int ii = 0; ii < 4; ++ii)
                        sp[rl][ii] += __shfl_xor(sp[rl][ii], off);
            if (colg == 0) {
#pragma unroll
                for (int rl = 0; rl < 2; ++rl)
#pragma unroll
                    for (int ii = 0; ii < 4; ++ii)
                        sm.part[wid][(mh * 2 + rl) * 16 + g * 4 + ii] = sp[rl][ii];
            }
        }
        __syncthreads();

        if (tid < 64) {   // softmax; row r lives in waves {2q + (r>=32)}
            const int hb = (tid >= 32) ? 1 : 0;
            float v = (tid < nrows) ? bvec[tid] : 0.f;
#pragma unroll
            for (int qq = 0; qq < 4; ++qq) v += sm.part[2 * qq + hb][tid];
            v = (tid < nrows) ? v : -3.0e38f;
            float mx = v;
#pragma unroll
            for (int off = 32; off; off >>= 1) mx = fmaxf(mx, __shfl_xor(mx, off));
            const float e = (tid < nrows) ? __expf(v - mx) : 0.f;
            float su = e;
#pragma unroll
            for (int off = 32; off; off >>= 1) su += __shfl_xor(su, off);
            sm.P[tid] = e / su;
        }
        __syncthreads();

        // ---- weighted sum from LDS bf16 (unrolled), atomic combine
        {
            float v = 0.f;
            if (pass == 0) {
#pragma unroll
                for (int r = 0; r < NR; ++r)
                    v += sm.P[r] * bf16_f32((unsigned short)
                         curb[(r << 9) + ((wch ^ (r & 7)) << 3) + wlo]);
            } else {
#pragma unroll
                for (int r = 0; r < NS; ++r)
                    v += sm.P[r] * bf16_f32((unsigned short)
                         curb[(r << 9) + ((wch ^ (r & 7)) << 3) + wlo]);
            }
            atomicAdd(&out[(size_t)(grp * NBATCH + i) * ND + tid], v);
        }
        __syncthreads();   // batch end: nxtb writes visible; curb free
    }
#undef LOADF
#undef WRITEF
}

extern "C" void kernel_launch(void* const* d_in, const int* in_sizes, int n_in,
                              void* d_out, int out_size, void* d_ws, size_t ws_size,
                              hipStream_t stream) {
    const float* ifeat = (const float*)d_in[0];
    const float* tfeat = (const float*)d_in[1];
    const float* wVi0  = (const float*)d_in[2];
    const float* wPi0  = (const float*)d_in[4];
    const float* bPi0  = (const float*)d_in[5];
    const float* wVt1  = (const float*)d_in[7];
    const float* wPi1  = (const float*)d_in[8];
    const float* bPi1  = (const float*)d_in[9];
    float* outp = (float*)d_out;
    unsigned short* wsW = (unsigned short*)d_ws;   // 2*114688 = 229376 B

    hipMemsetAsync(outp, 0, (size_t)NB * ND * sizeof(float), stream);
    hipLaunchKernelGGL(preswz_kernel, dim3(NT * KSTEPS, 2), dim3(64), 0, stream,
                       wVi0, wVt1, wsW);
    hipLaunchKernelGGL(coattn_main, dim3(2 * NGRP), dim3(512), 0, stream,
                       ifeat, tfeat, wPi0, bPi0, wPi1, bPi1, wsW, outp);
}